// Round 7
// baseline (425.301 us; speedup 1.0000x reference)
//
#include <hip/hip_runtime.h>
#include <hip/hip_bf16.h>

// Problem constants
#define BB 8
#define SS 2048
#define DD 1024
#define OO 1024
#define MM (BB * SS)   // 16384
#define KK DD          // 1024
#define NN OO          // 1024
#define CC 64          // chunks
#define LL 32          // chunk length (CC*LL == SS)

typedef __bf16 bf16x8 __attribute__((ext_vector_type(8)));
typedef __bf16 bf16x2 __attribute__((ext_vector_type(2)));
typedef float floatx4 __attribute__((ext_vector_type(4)));

__device__ __forceinline__ float2 fma2(float2 h, float2 a, float2 v) {
    h.x = fmaf(h.x, a.x, v.x);
    h.y = fmaf(h.y, a.y, v.y);
    return h;
}

// ---------------- Fused scan (plain launch + decoupled lookback) ----------------
// 768 blocks x 512 thr. Blocks 0..511 = (b,c) scan chunks; 512..767 = BC
// transpose (4 tiles each). All blocks co-resident by construction
// (<=64 VGPR, 4.6KB LDS -> 4 blocks/CU capacity = 1024 >= 768), so the
// flag-wait cannot deadlock. Protocol (documented device-scope pattern):
//   produce: carry stores -> __threadfence() -> __syncthreads -> atomic flag=1
//   consume: thread j<c spins on flag j (parallel, straggler-bounded)
//            -> __syncthreads -> __threadfence() -> carry loads
// Flags live in d_out[0..511] (memset on-stream before this kernel; gemm
// overwrites the region with real C values afterwards).
// All fma chains identical to the verified 2-kernel version -> same absmax.
__global__ __launch_bounds__(512) void scan_fused(const float* __restrict__ x,
                                                  const float* __restrict__ A,
                                                  float* __restrict__ carry,
                                                  const float* __restrict__ BC,
                                                  __bf16* __restrict__ BCt,
                                                  __bf16* __restrict__ hs,
                                                  unsigned int* __restrict__ flags) {
    __shared__ float tile[32][33];
    const int id = blockIdx.x;
    if (id >= BB * CC) {
        // ---- BC transpose+cast: 4 of the 1024 32x32 tiles per block
        const int tx = threadIdx.x & 31;
        const int ty = threadIdx.x >> 5;   // 0..15
#pragma unroll
        for (int w = 0; w < 4; ++w) {
            const int t = (id - BB * CC) * 4 + w;
            const int o0 = (t & 31) * 32;
            const int d0 = (t >> 5) * 32;
            __syncthreads();               // tile reuse across w
#pragma unroll
            for (int i = 0; i < 2; ++i) {
                const int dd = ty + i * 16;
                tile[dd][tx] = BC[(size_t)(d0 + dd) * OO + o0 + tx];
            }
            __syncthreads();
#pragma unroll
            for (int i = 0; i < 2; ++i) {
                const int oo = ty + i * 16;
                BCt[(size_t)(o0 + oo) * DD + d0 + tx] = (__bf16)tile[tx][oo];
            }
        }
        return;
    }

    const int c = id & (CC - 1);
    const int b = id >> 6;
    const int i2 = threadIdx.x;     // float2 index over D (0..511)
    const float2 a = ((const float2*)A)[i2];
    const size_t base = ((size_t)b * SS + (size_t)c * LL) * DD;
    const float2* xp = (const float2*)(x + base) + i2;

    // ---- local chunk scan -> carry
    {
        float2 h = make_float2(0.f, 0.f);
#pragma unroll
        for (int t0 = 0; t0 < LL; t0 += 8) {
            float2 v[8];
#pragma unroll
            for (int u = 0; u < 8; ++u) v[u] = xp[(size_t)(t0 + u) * (DD / 2)];
#pragma unroll
            for (int u = 0; u < 8; ++u) h = fma2(h, a, v[u]);
        }
        ((float2*)carry)[((size_t)b * CC + c) * (DD / 2) + i2] = h;
    }
    __threadfence();                 // publish carry device-wide (L2 wb)
    __syncthreads();                 // all threads' stores fenced
    if (threadIdx.x == 0) atomicExch(&flags[id], 1u);

    // ---- wait for predecessors: thread j polls flag j (parallel wait)
    if ((int)threadIdx.x < c) {
        while (atomicAdd(&flags[(b << 6) + threadIdx.x], 0u) == 0u)
            __builtin_amdgcn_s_sleep(2);
    }
    __syncthreads();
    __threadfence();                 // acquire: no stale carry lines

    // ---- chunk prefix (batched 8-deep, ascending j: same rounding)
    float2 aL = a;
#pragma unroll
    for (int i = 0; i < 5; ++i) { aL.x *= aL.x; aL.y *= aL.y; }   // a^32
    float2 h = make_float2(0.f, 0.f);
    const float2* cp = (const float2*)carry + (size_t)b * CC * (DD / 2) + i2;
    int j = 0;
    for (; j + 8 <= c; j += 8) {
        float2 cv[8];
#pragma unroll
        for (int u = 0; u < 8; ++u) cv[u] = cp[(size_t)(j + u) * (DD / 2)];
#pragma unroll
        for (int u = 0; u < 8; ++u) h = fma2(h, aL, cv[u]);
    }
    for (; j < c; ++j) h = fma2(h, aL, cp[(size_t)j * (DD / 2)]);

    // ---- emit hs (x re-read is L2/L3-hot from the local-scan pass)
    bf16x2* hp = (bf16x2*)(hs + base) + i2;
#pragma unroll
    for (int t0 = 0; t0 < LL; t0 += 8) {
        float2 v[8];
#pragma unroll
        for (int u = 0; u < 8; ++u) v[u] = xp[(size_t)(t0 + u) * (DD / 2)];
#pragma unroll
        for (int u = 0; u < 8; ++u) {
            h = fma2(h, a, v[u]);
            bf16x2 o;
            o[0] = (__bf16)h.x; o[1] = (__bf16)h.y;
            hp[(size_t)(t0 + u) * (DD / 2)] = o;
        }
    }
}

// ---------------- GEMM: C[m,n] = sum_k A[m,k] * Bt[n,k] ----------------
// (byte-identical to round 4/6 — verified 46.8 us, SQ_LDS_BANK_CONFLICT=0)
// 256x256 tile, BK=64, 8 waves (2Mx4N). ONE vmcnt(0) + ONE barrier per
// K-tile, all stages strictly AFTER the barrier.
#define GTM 256
#define GTN 256
#define GTK 64
#define GNT (KK / GTK)   // 16

__device__ __forceinline__ void async16(void* lds, const void* g) {
    __builtin_amdgcn_global_load_lds(
        (__attribute__((address_space(1))) void*)(void*)g,
        (__attribute__((address_space(3))) void*)lds, 16, 0, 0);
}

#define MEMFENCE asm volatile("" ::: "memory")
#define BARRIER do { MEMFENCE; __builtin_amdgcn_s_barrier(); MEMFENCE; } while (0)
#define VMCNT0 asm volatile("s_waitcnt vmcnt(0)" ::: "memory")

__global__ __launch_bounds__(512, 2) void gemm_bt(const __bf16* __restrict__ Am,
                                                  const __bf16* __restrict__ Bt,
                                                  float* __restrict__ C) {
    __shared__ __align__(16) __bf16 As[2][GTM * GTK];   // 2 x 32 KB
    __shared__ __align__(16) __bf16 Bs[2][GTN * GTK];   // 2 x 32 KB

    const int tid = threadIdx.x;          // 0..511
    const int wave = tid >> 6;            // 0..7
    const int lane = tid & 63;
    const int wm = (wave >> 2) * 128;     // 0 / 128
    const int wn = (wave & 3) * 64;       // 0,64,128,192
    const int lanelo = lane & 15;
    const int quad = lane >> 4;

    // XCD-chunked swizzle (FETCH_SIZE 38->24.6 MB)
    const int bid = blockIdx.x;
    const int xcd = bid & 7;
    const int loc = bid >> 3;             // 0..31
    const int tile_m = (xcd * 8 + (loc >> 2)) * GTM;
    const int tile_n = (loc & 3) * GTN;

    // ---- staging pointers: slabs {0:A-M0, 1:B-N0, 2:B-N1, 3:A-M1} x 2 loads
    const __bf16* gsrc[4][2];
    int ldsoff[4][2];
#pragma unroll
    for (int a = 0; a < 2; ++a)
#pragma unroll
        for (int u = 0; u < 2; ++u) {
            const int idx = a * 1024 + u * 512 + tid;   // LDS chunk id
            const int rho = idx >> 3, qs = idx & 7;
            const int rl = rho & 127;
            const int r = (rl >> 6) * 128 + a * 64 + (rl & 63);  // global row
            const int qg = qs ^ (rho & 7);
            gsrc[a * 3][u] = Am + (size_t)(tile_m + r) * KK + qg * 8;
            ldsoff[a * 3][u] = idx * 8;
        }
#pragma unroll
    for (int b = 0; b < 2; ++b)
#pragma unroll
        for (int u = 0; u < 2; ++u) {
            const int idx = b * 1024 + u * 512 + tid;
            const int rho = idx >> 3, qs = idx & 7;
            const int rl = rho & 127;
            const int r = (rl >> 5) * 64 + b * 32 + (rl & 31);   // global row
            const int qg = qs ^ (rho & 7);
            gsrc[1 + b][u] = Bt + (size_t)(tile_n + r) * KK + qg * 8;
            ldsoff[1 + b][u] = idx * 8;
        }

    auto stage = [&](int p, int bufi, int koff) {
        __bf16* base = (p == 0 || p == 3) ? As[bufi] : Bs[bufi];
#pragma unroll
        for (int u = 0; u < 2; ++u)
            async16(base + ldsoff[p][u], gsrc[p][u] + koff);
    };

    floatx4 acc[8][4];
#pragma unroll
    for (int i = 0; i < 8; ++i)
#pragma unroll
        for (int j = 0; j < 4; ++j) acc[i][j] = (floatx4){0.f, 0.f, 0.f, 0.f};

    bf16x8 af[4][2];        // current M-half A fragments
    bf16x8 bv[2][2][2];     // [Nhalf][jl][kk], both halves held

    auto read_a = [&](const __bf16* as, int mh) {
#pragma unroll
        for (int il = 0; il < 4; ++il)
#pragma unroll
            for (int kk = 0; kk < 2; ++kk) {
                const int rho = mh * 128 + (wm >> 1) + il * 16 + lanelo;
                af[il][kk] = *(const bf16x8*)(as + rho * 64 + (((kk * 4 + quad) ^ (lanelo & 7)) * 8));
            }
    };
    auto read_b = [&](const __bf16* bs, int nh) {
#pragma unroll
        for (int jl = 0; jl < 2; ++jl)
#pragma unroll
            for (int kk = 0; kk < 2; ++kk) {
                const int rho = nh * 128 + (wn >> 1) + jl * 16 + lanelo;
                bv[nh][jl][kk] = *(const bf16x8*)(bs + rho * 64 + (((kk * 4 + quad) ^ (lanelo & 7)) * 8));
            }
    };
    auto mfma16 = [&](int mh, int nh) {
        __builtin_amdgcn_s_setprio(1);
#pragma unroll
        for (int il = 0; il < 4; ++il)
#pragma unroll
            for (int jl = 0; jl < 2; ++jl)
#pragma unroll
                for (int kk = 0; kk < 2; ++kk)
                    acc[mh * 4 + il][nh * 2 + jl] = __builtin_amdgcn_mfma_f32_16x16x32_bf16(
                        af[il][kk], bv[nh][jl][kk], acc[mh * 4 + il][nh * 2 + jl], 0, 0, 0);
        __builtin_amdgcn_s_setprio(0);
    };
    auto store_q = [&](int mh, int nh) {
#pragma unroll
        for (int il = 0; il < 4; ++il) {
            const int row = tile_m + wm + (mh * 4 + il) * 16 + quad * 4;
#pragma unroll
            for (int r = 0; r < 4; ++r) {
                float* crow = C + (size_t)(row + r) * NN + tile_n + wn + lanelo;
#pragma unroll
                for (int jl = 0; jl < 2; ++jl)
                    crow[(nh * 2 + jl) * 16] = acc[mh * 4 + il][nh * 2 + jl][r];
            }
        }
    };

    // prologue: tile 0, all 4 slabs -> buf 0 (8 loads in flight)
    stage(0, 0, 0);
    stage(3, 0, 0);
    stage(1, 0, 0);
    stage(2, 0, 0);

    for (int t = 0; t < GNT - 1; ++t) {
        const int cur = t & 1, nxt = cur ^ 1;
        const __bf16* as = As[cur];
        const __bf16* bs = Bs[cur];
        const int ko = (t + 1) * GTK;

        VMCNT0;                   // tile t's 8 loads retired (issued 1 tile ago)
        BARRIER;                  // publish tile t; release buf[nxt] for overwrite

        stage(0, nxt, ko);        // all stages AFTER the barrier
        stage(3, nxt, ko);
        stage(1, nxt, ko);
        stage(2, nxt, ko);

        read_a(as, 0);
        read_b(bs, 0);
        mfma16(0, 0);

        read_b(bs, 1);
        mfma16(0, 1);

        read_a(as, 1);
        mfma16(1, 1);

        mfma16(1, 0);
    }

    // tail tile: drain, then interleave quadrant stores with final MFMAs
    {
        const __bf16* as = As[(GNT - 1) & 1];
        const __bf16* bs = Bs[(GNT - 1) & 1];
        VMCNT0;
        BARRIER;
        read_a(as, 0);
        read_b(bs, 0);
        mfma16(0, 0);
        read_b(bs, 1);
        mfma16(0, 1);
        store_q(0, 0);            // acc[0..3][0..1] final
        read_a(as, 1);
        mfma16(1, 1);
        store_q(0, 1);            // acc[0..3][2..3] final
        mfma16(1, 0);
        store_q(1, 0);
        store_q(1, 1);
    }
}

extern "C" void kernel_launch(void* const* d_in, const int* in_sizes, int n_in,
                              void* d_out, int out_size, void* d_ws, size_t ws_size,
                              hipStream_t stream) {
    const float* x  = (const float*)d_in[0];   // [B,S,D]
    const float* A  = (const float*)d_in[1];   // [D]
    const float* BC = (const float*)d_in[2];   // [D,O]
    float* out = (float*)d_out;                // [B,S,O]

    char* ws = (char*)d_ws;
    __bf16* hs   = (__bf16*)ws;                                  // 33,554,432 B
    float* carry = (float*)(ws + 33554432);                      // 2 MB (BB*CC*DD*4)
    __bf16* BCt  = (__bf16*)(ws + 33554432 + 2097152);           // 2 MB

    // Flags borrow the first 2 KB of the output buffer: zeroed on-stream,
    // consumed by scan_fused, then overwritten by gemm with real C values.
    unsigned int* flags = (unsigned int*)d_out;
    hipMemsetAsync(flags, 0, BB * CC * sizeof(unsigned int), stream);

    scan_fused<<<dim3(BB * CC + 256), 512, 0, stream>>>(x, A, carry, BC, BCt, hs, flags);
    gemm_bt<<<dim3(MM / GTM * (NN / GTN)), 512, 0, stream>>>(hs, BCt, out);
}

// Round 8
// 169.728 us; speedup vs baseline: 2.5058x; 2.5058x over previous
//
#include <hip/hip_runtime.h>
#include <hip/hip_bf16.h>

// Problem constants
#define BB 8
#define SS 2048
#define DD 1024
#define OO 1024
#define MM (BB * SS)   // 16384
#define KK DD          // 1024
#define NN OO          // 1024
#define CC 64          // chunks
#define LL 32          // chunk length (CC*LL == SS)

typedef __bf16 bf16x8 __attribute__((ext_vector_type(8)));
typedef __bf16 bf16x2 __attribute__((ext_vector_type(2)));
typedef float floatx4 __attribute__((ext_vector_type(4)));

__device__ __forceinline__ float2 fma2(float2 h, float2 a, float2 v) {
    h.x = fmaf(h.x, a.x, v.x);
    h.y = fmaf(h.y, a.y, v.y);
    return h;
}

// ---------------- Kernel 1: per-chunk carries (float2 lanes, 512 thr) + BC transpose ----------------
// (unchanged from round 6 — verified)
__global__ __launch_bounds__(512) void prep(const float* __restrict__ x,
                                            const float* __restrict__ A,
                                            float* __restrict__ carry,
                                            const float* __restrict__ BC,
                                            __bf16* __restrict__ BCt) {
    __shared__ float tile[32][33];
    const int id = blockIdx.x;
    if (id < BB * CC) {
        const int c = id & (CC - 1);
        const int b = id >> 6;          // id / CC
        const int i2 = threadIdx.x;     // float2 index over D (0..511)
        const float2 a = ((const float2*)A)[i2];
        const float2* xp = (const float2*)(x + ((size_t)b * SS + (size_t)c * LL) * DD) + i2;
        float2 h = make_float2(0.f, 0.f);
#pragma unroll
        for (int t0 = 0; t0 < LL; t0 += 8) {
            float2 v[8];
#pragma unroll
            for (int u = 0; u < 8; ++u) v[u] = xp[(size_t)(t0 + u) * (DD / 2)];
#pragma unroll
            for (int u = 0; u < 8; ++u) h = fma2(h, a, v[u]);
        }
        ((float2*)carry)[((size_t)b * CC + c) * (DD / 2) + i2] = h;
    } else {
        const int t = id - BB * CC;        // 0..1023 transpose tiles
        const int o0 = (t & 31) * 32;
        const int d0 = (t >> 5) * 32;
        const int tx = threadIdx.x & 31;
        const int ty = threadIdx.x >> 5;   // 0..15
#pragma unroll
        for (int i = 0; i < 2; ++i) {
            const int dd = ty + i * 16;
            tile[dd][tx] = BC[(size_t)(d0 + dd) * OO + o0 + tx];
        }
        __syncthreads();
#pragma unroll
        for (int i = 0; i < 2; ++i) {
            const int oo = ty + i * 16;
            BCt[(size_t)(o0 + oo) * DD + d0 + tx] = (__bf16)tile[tx][oo];
        }
    }
}

// ---------------- Kernel 2: emit hs (bf16); prefix batched 8-deep ----------------
// (unchanged from round 6 — verified)
__global__ __launch_bounds__(512) void scan_emit(const float* __restrict__ x,
                                                 const float* __restrict__ A,
                                                 const float* __restrict__ carry,
                                                 __bf16* __restrict__ hs) {
    const int id = blockIdx.x;
    const int c = id & (CC - 1);
    const int b = id >> 6;
    const int i2 = threadIdx.x;     // float2 index over D (0..511)
    const float2 a = ((const float2*)A)[i2];
    float2 aL = a;
#pragma unroll
    for (int i = 0; i < 5; ++i) { aL.x *= aL.x; aL.y *= aL.y; }   // a^32
    float2 h = make_float2(0.f, 0.f);
    const float2* cp = (const float2*)carry + (size_t)b * CC * (DD / 2) + i2;
    int j = 0;
    for (; j + 8 <= c; j += 8) {
        float2 cv[8];
#pragma unroll
        for (int u = 0; u < 8; ++u) cv[u] = cp[(size_t)(j + u) * (DD / 2)];
#pragma unroll
        for (int u = 0; u < 8; ++u) h = fma2(h, aL, cv[u]);
    }
    for (; j < c; ++j) h = fma2(h, aL, cp[(size_t)j * (DD / 2)]);

    const size_t base = ((size_t)b * SS + (size_t)c * LL) * DD;
    const float2* xp = (const float2*)(x + base) + i2;
    bf16x2* hp = (bf16x2*)(hs + base) + i2;
#pragma unroll
    for (int t0 = 0; t0 < LL; t0 += 8) {
        float2 v[8];
#pragma unroll
        for (int u = 0; u < 8; ++u) v[u] = xp[(size_t)(t0 + u) * (DD / 2)];
#pragma unroll
        for (int u = 0; u < 8; ++u) {
            h = fma2(h, a, v[u]);
            bf16x2 o;
            o[0] = (__bf16)h.x; o[1] = (__bf16)h.y;
            hp[(size_t)(t0 + u) * (DD / 2)] = o;
        }
    }
}

// ---------------- GEMM: C[m,n] = sum_k A[m,k] * Bt[n,k] ----------------
// 256x256 tile, BK=64, 8 waves (2Mx4N). Staging/sync skeleton identical to
// round 6 (proven race-free): ONE vmcnt(0) + ONE tile-top barrier, all
// stages strictly after it. NEW (m201 per-phase re-stagger): the 4 MFMA
// quadrants are separated by phase barriers with asm lgkmcnt(0) +
// sched_barrier(0) before each 16-MFMA cluster. Each phase: {issue next
// quadrant's ds_reads; s_barrier; lgkmcnt(0); pinned MFMA cluster} — a
// wave's ds_reads fly while other waves are still in their MFMA cluster,
// overlapping the DS pipe (the binding pipe: 192KB LDS reads/tile ~2300cyc
// vs 620cyc MFMA) with the MFMA pipes, re-staggered every 16 MFMAs.
// Extra barriers are correctness-neutral (symmetric, equal counts).
#define GTM 256
#define GTN 256
#define GTK 64
#define GNT (KK / GTK)   // 16

__device__ __forceinline__ void async16(void* lds, const void* g) {
    __builtin_amdgcn_global_load_lds(
        (__attribute__((address_space(1))) void*)(void*)g,
        (__attribute__((address_space(3))) void*)lds, 16, 0, 0);
}

#define MEMFENCE asm volatile("" ::: "memory")
#define BARRIER do { MEMFENCE; __builtin_amdgcn_s_barrier(); MEMFENCE; } while (0)
#define VMCNT0 asm volatile("s_waitcnt vmcnt(0)" ::: "memory")
#define LGKM0  asm volatile("s_waitcnt lgkmcnt(0)" ::: "memory")
#define SCHED0 __builtin_amdgcn_sched_barrier(0)

__global__ __launch_bounds__(512, 2) void gemm_bt(const __bf16* __restrict__ Am,
                                                  const __bf16* __restrict__ Bt,
                                                  float* __restrict__ C) {
    __shared__ __align__(16) __bf16 As[2][GTM * GTK];   // 2 x 32 KB
    __shared__ __align__(16) __bf16 Bs[2][GTN * GTK];   // 2 x 32 KB

    const int tid = threadIdx.x;          // 0..511
    const int wave = tid >> 6;            // 0..7
    const int lane = tid & 63;
    const int wm = (wave >> 2) * 128;     // 0 / 128
    const int wn = (wave & 3) * 64;       // 0,64,128,192
    const int lanelo = lane & 15;
    const int quad = lane >> 4;

    // XCD-chunked swizzle (FETCH_SIZE 38->24.6 MB)
    const int bid = blockIdx.x;
    const int xcd = bid & 7;
    const int loc = bid >> 3;             // 0..31
    const int tile_m = (xcd * 8 + (loc >> 2)) * GTM;
    const int tile_n = (loc & 3) * GTN;

    // ---- staging pointers: slabs {0:A-M0, 1:B-N0, 2:B-N1, 3:A-M1} x 2 loads
    const __bf16* gsrc[4][2];
    int ldsoff[4][2];
#pragma unroll
    for (int a = 0; a < 2; ++a)
#pragma unroll
        for (int u = 0; u < 2; ++u) {
            const int idx = a * 1024 + u * 512 + tid;   // LDS chunk id
            const int rho = idx >> 3, qs = idx & 7;
            const int rl = rho & 127;
            const int r = (rl >> 6) * 128 + a * 64 + (rl & 63);  // global row
            const int qg = qs ^ (rho & 7);
            gsrc[a * 3][u] = Am + (size_t)(tile_m + r) * KK + qg * 8;
            ldsoff[a * 3][u] = idx * 8;
        }
#pragma unroll
    for (int b = 0; b < 2; ++b)
#pragma unroll
        for (int u = 0; u < 2; ++u) {
            const int idx = b * 1024 + u * 512 + tid;
            const int rho = idx >> 3, qs = idx & 7;
            const int rl = rho & 127;
            const int r = (rl >> 5) * 64 + b * 32 + (rl & 31);   // global row
            const int qg = qs ^ (rho & 7);
            gsrc[1 + b][u] = Bt + (size_t)(tile_n + r) * KK + qg * 8;
            ldsoff[1 + b][u] = idx * 8;
        }

    auto stage = [&](int p, int bufi, int koff) {
        __bf16* base = (p == 0 || p == 3) ? As[bufi] : Bs[bufi];
#pragma unroll
        for (int u = 0; u < 2; ++u)
            async16(base + ldsoff[p][u], gsrc[p][u] + koff);
    };

    floatx4 acc[8][4];
#pragma unroll
    for (int i = 0; i < 8; ++i)
#pragma unroll
        for (int j = 0; j < 4; ++j) acc[i][j] = (floatx4){0.f, 0.f, 0.f, 0.f};

    bf16x8 af[4][2];        // current M-half A fragments
    bf16x8 bv[2][2][2];     // [Nhalf][jl][kk], both halves held

    auto read_a = [&](const __bf16* as, int mh) {
#pragma unroll
        for (int il = 0; il < 4; ++il)
#pragma unroll
            for (int kk = 0; kk < 2; ++kk) {
                const int rho = mh * 128 + (wm >> 1) + il * 16 + lanelo;
                af[il][kk] = *(const bf16x8*)(as + rho * 64 + (((kk * 4 + quad) ^ (lanelo & 7)) * 8));
            }
    };
    auto read_b = [&](const __bf16* bs, int nh) {
#pragma unroll
        for (int jl = 0; jl < 2; ++jl)
#pragma unroll
            for (int kk = 0; kk < 2; ++kk) {
                const int rho = nh * 128 + (wn >> 1) + jl * 16 + lanelo;
                bv[nh][jl][kk] = *(const bf16x8*)(bs + rho * 64 + (((kk * 4 + quad) ^ (lanelo & 7)) * 8));
            }
    };
    auto mfma16 = [&](int mh, int nh) {
        __builtin_amdgcn_s_setprio(1);
#pragma unroll
        for (int il = 0; il < 4; ++il)
#pragma unroll
            for (int jl = 0; jl < 2; ++jl)
#pragma unroll
                for (int kk = 0; kk < 2; ++kk)
                    acc[mh * 4 + il][nh * 2 + jl] = __builtin_amdgcn_mfma_f32_16x16x32_bf16(
                        af[il][kk], bv[nh][jl][kk], acc[mh * 4 + il][nh * 2 + jl], 0, 0, 0);
        __builtin_amdgcn_s_setprio(0);
    };
    auto store_q = [&](int mh, int nh) {
#pragma unroll
        for (int il = 0; il < 4; ++il) {
            const int row = tile_m + wm + (mh * 4 + il) * 16 + quad * 4;
#pragma unroll
            for (int r = 0; r < 4; ++r) {
                float* crow = C + (size_t)(row + r) * NN + tile_n + wn + lanelo;
#pragma unroll
                for (int jl = 0; jl < 2; ++jl)
                    crow[(nh * 2 + jl) * 16] = acc[mh * 4 + il][nh * 2 + jl][r];
            }
        }
    };

    // prologue: tile 0, all 4 slabs -> buf 0 (8 loads in flight)
    stage(0, 0, 0);
    stage(3, 0, 0);
    stage(1, 0, 0);
    stage(2, 0, 0);

    for (int t = 0; t < GNT - 1; ++t) {
        const int cur = t & 1, nxt = cur ^ 1;
        const __bf16* as = As[cur];
        const __bf16* bs = Bs[cur];
        const int ko = (t + 1) * GTK;

        VMCNT0;                   // tile t's 8 loads retired (issued 1 tile ago)
        BARRIER;                  // publish tile t; release buf[nxt] for overwrite

        stage(0, nxt, ko);        // all stages AFTER the tile-top barrier
        stage(3, nxt, ko);
        stage(1, nxt, ko);
        stage(2, nxt, ko);

        // phase 0: quadrant (M0,N0)
        read_a(as, 0);
        read_b(bs, 0);
        BARRIER; LGKM0; SCHED0;
        mfma16(0, 0);

        // phase 1: quadrant (M0,N1) — reads issued while others still MFMA p0
        read_b(bs, 1);
        BARRIER; LGKM0; SCHED0;
        mfma16(0, 1);

        // phase 2: quadrant (M1,N1)
        read_a(as, 1);
        BARRIER; LGKM0; SCHED0;
        mfma16(1, 1);

        // phase 3: quadrant (M1,N0) — bv[0] still live, no reads, no barrier
        mfma16(1, 0);
    }

    // tail tile: drain, then interleave quadrant stores with final MFMAs
    {
        const __bf16* as = As[(GNT - 1) & 1];
        const __bf16* bs = Bs[(GNT - 1) & 1];
        VMCNT0;
        BARRIER;
        read_a(as, 0);
        read_b(bs, 0);
        mfma16(0, 0);
        read_b(bs, 1);
        mfma16(0, 1);
        store_q(0, 0);            // acc[0..3][0..1] final
        read_a(as, 1);
        mfma16(1, 1);
        store_q(0, 1);            // acc[0..3][2..3] final
        mfma16(1, 0);
        store_q(1, 0);
        store_q(1, 1);
    }
}

extern "C" void kernel_launch(void* const* d_in, const int* in_sizes, int n_in,
                              void* d_out, int out_size, void* d_ws, size_t ws_size,
                              hipStream_t stream) {
    const float* x  = (const float*)d_in[0];   // [B,S,D]
    const float* A  = (const float*)d_in[1];   // [D]
    const float* BC = (const float*)d_in[2];   // [D,O]
    float* out = (float*)d_out;                // [B,S,O]

    char* ws = (char*)d_ws;
    __bf16* hs   = (__bf16*)ws;                                  // 33,554,432 B
    float* carry = (float*)(ws + 33554432);                      // 2 MB (BB*CC*DD*4)
    __bf16* BCt  = (__bf16*)(ws + 33554432 + 2097152);           // 2 MB

    prep<<<dim3(BB * CC + 1024), 512, 0, stream>>>(x, A, carry, BC, BCt);
    scan_emit<<<dim3(BB * CC), 512, 0, stream>>>(x, A, carry, hs);
    gemm_bt<<<dim3(MM / GTM * (NN / GTN)), 512, 0, stream>>>(hs, BCt, out);
}